// Round 9
// baseline (3513.581 us; speedup 1.0000x reference)
//
#include <hip/hip_runtime.h>
#include <hip/hip_bf16.h>

#define BB 64
#define SS 512
#define HH 1024
#define G4 4096

using bf8_t = __attribute__((ext_vector_type(8))) short;   // 8 bf16 (4 VGPRs)
using f32x4 = __attribute__((ext_vector_type(4))) float;   // 4 fp32 acc

__device__ inline ushort f2bf(float f) {
  __hip_bfloat16 h = __float2bfloat16(f);
  return *reinterpret_cast<ushort*>(&h);
}
__device__ inline float bf2f(ushort u) {
  unsigned v = ((unsigned)u) << 16;
  return __uint_as_float(v);
}

// fp32 [R][C] -> bf16 [C][R]
__global__ __launch_bounds__(256) void k_transpose_cast(
    const float* __restrict__ in, ushort* __restrict__ out, int R, int C) {
  __shared__ float tile[32][33];
  int c0 = blockIdx.x * 32, r0 = blockIdx.y * 32;
  int tx = threadIdx.x & 31, ty = threadIdx.x >> 5;  // 32 x 8
  for (int i = ty; i < 32; i += 8) {
    int r = r0 + i, c = c0 + tx;
    tile[i][tx] = (r < R && c < C) ? in[(size_t)r * C + c] : 0.f;
  }
  __syncthreads();
  for (int i = ty; i < 32; i += 8) {
    int c = c0 + i, r = r0 + tx;
    if (c < C && r < R) out[(size_t)c * R + r] = f2bf(tile[tx][i]);
  }
}

// Ae[row = t*64+b][k] = embed_tok[x[b][t]][k] + embed_pos[t][k], bf16
__global__ __launch_bounds__(256) void k_embed(
    const int* __restrict__ x, const float* __restrict__ etok,
    const float* __restrict__ epos, ushort* __restrict__ Ae) {
  int row = blockIdx.x;
  int t = row >> 6, b = row & 63;
  int tok = x[b * SS + t];
  const float4* tp = (const float4*)(etok + (size_t)tok * HH);
  const float4* pp = (const float4*)(epos + (size_t)t * HH);
  int i = threadIdx.x;  // 256 threads * float4 = 1024
  float4 a = tp[i], p = pp[i];
  ushort4 r = make_ushort4(f2bf(a.x + p.x), f2bf(a.y + p.y),
                           f2bf(a.z + p.z), f2bf(a.w + p.w));
  ((ushort4*)(Ae + (size_t)row * HH))[i] = r;
}

// C[m][n] (bf16) = A[m][k] @ Bt[n][k]^T + bias[n].  M,N mult of 128, K=1024.
__global__ __launch_bounds__(256) void k_gemm_xi(
    const ushort* __restrict__ Ag, const ushort* __restrict__ Bt,
    const float* __restrict__ bias, ushort* __restrict__ Cout, int N) {
  __shared__ alignas(16) ushort As[128 * 40];   // rows padded 32->40 shorts
  __shared__ alignas(16) ushort Bs[128 * 40];
  const int m0 = blockIdx.y * 128, n0 = blockIdx.x * 128;
  const int tid = threadIdx.x;
  const int srow = tid >> 1, shalf = tid & 1;   // stage: 2 thr/row, 16 shorts each
  const int w = tid >> 6, lane = tid & 63;
  const int wm = w >> 1, wn = w & 1;            // 2x2 waves, 64x64 each
  const int lr = lane & 15, kq = lane >> 4;
  f32x4 acc[4][4] = {};
  for (int k0 = 0; k0 < HH; k0 += 32) {
    const uint4* ga = (const uint4*)(Ag + (size_t)(m0 + srow) * HH + k0 + shalf * 16);
    const uint4* gb = (const uint4*)(Bt + (size_t)(n0 + srow) * HH + k0 + shalf * 16);
    uint4 va0 = ga[0], va1 = ga[1];
    uint4 vb0 = gb[0], vb1 = gb[1];
    __syncthreads();
    *(uint4*)&As[srow * 40 + shalf * 16]     = va0;
    *(uint4*)&As[srow * 40 + shalf * 16 + 8] = va1;
    *(uint4*)&Bs[srow * 40 + shalf * 16]     = vb0;
    *(uint4*)&Bs[srow * 40 + shalf * 16 + 8] = vb1;
    __syncthreads();
    bf8_t fa[4], fb[4];
#pragma unroll
    for (int i = 0; i < 4; ++i) {
      fa[i] = *(const bf8_t*)&As[(wm * 64 + i * 16 + lr) * 40 + kq * 8];
      fb[i] = *(const bf8_t*)&Bs[(wn * 64 + i * 16 + lr) * 40 + kq * 8];
    }
#pragma unroll
    for (int mi = 0; mi < 4; ++mi)
#pragma unroll
      for (int ni = 0; ni < 4; ++ni)
        acc[mi][ni] = __builtin_amdgcn_mfma_f32_16x16x32_bf16(fa[mi], fb[ni], acc[mi][ni], 0, 0, 0);
  }
#pragma unroll
  for (int mi = 0; mi < 4; ++mi) {
    int grow = m0 + wm * 64 + mi * 16 + kq * 4;
#pragma unroll
    for (int ni = 0; ni < 4; ++ni) {
      int gcol = n0 + wn * 64 + ni * 16 + lr;
      float bv = bias[gcol];
#pragma unroll
      for (int r = 0; r < 4; ++r)
        Cout[(size_t)(grow + r) * N + gcol] = f2bf(acc[mi][ni][r] + bv);
    }
  }
}

// Persistent recurrence, 4 batch groups x 64 column-owner WGs.
// DATA-IS-FLAG transport: fragA pre-filled with sentinel 0x7F7F... (bf16
// 3.4e38 — impossible for |h|<1). Producers publish 8B units via relaxed
// agent atomic exchange (performed at MALL); consumers poll THEIR OWN units
// with relaxed agent 8B atomic loads until != sentinel. No flags, no acks,
// no fences: the successful poll IS the data load. 2 barriers/step.
__global__ __launch_bounds__(256, 1) void k_recur(
    const ushort* __restrict__ Wh_t,   // [4096][1024] bf16
    const ushort* __restrict__ xi,     // [S*64][4096] bf16 (bh folded in)
    ushort* __restrict__ hs,           // [(S+1)*64][1024] bf16 row layout
    uint4* __restrict__ fragA,         // [512][4][2048] 16B units: h(t+1) at t
    const uint4* __restrict__ zfrag) { // [4][2048] zeros (h(0))
  __shared__ alignas(16) ushort htile[2048 * 8];   // 32 KiB: full h tile
  __shared__ alignas(16) float zbuf[4][16][17];    // 4.25 KiB
  const unsigned long long SENT = 0x7F7F7F7F7F7F7F7FULL;
  const int grp = blockIdx.x >> 6;      // batch group 0..3
  const int mem = blockIdx.x & 63;      // member in group (column owner)
  const int n0 = mem * 16;
  const int brow0 = grp * 16;
  const int tid = threadIdx.x;
  const int w = tid >> 6, lane = tid & 63;
  const int lr = lane & 15, kq = lane >> 4;

  // fb fragments from global (read-only, L2-resident after step 0).
  // fbr[k] = Wh gate w, cols n0..n0+16, k-chunk k (fragment order)
  bf8_t fbr[32];
  {
    const ushort* wrow = Wh_t + (size_t)(w * 1024 + n0 + lr) * HH + kq * 8;
#pragma unroll
    for (int k = 0; k < 32; ++k) fbr[k] = *(const bf8_t*)(wrow + k * 32);
#pragma unroll
    for (int k = 0; k < 32; ++k) asm volatile("" : "+v"(fbr[k]));
  }

  // epilogue ownership (wave 0): batch row eb, cols pc..pc+3
  const int eb = lane >> 2, en4 = (lane & 3) * 4;
  const int pc = n0 + en4;
  const int pk = pc >> 5, pkq = (pc >> 3) & 3;
  const int pubu = pk * 64 + pkq * 16 + eb;     // 16B unit in group block
  const int pubb = (pc & 7) * 2;                // byte offset 0 or 8
  float cr[4] = {0.f, 0.f, 0.f, 0.f};

  // xi(0) preload (wave 0)
  ushort4 xv[4] = {};
  if (w == 0) {
    const ushort* xb = xi + ((size_t)brow0 + eb) * G4 + pc;
#pragma unroll
    for (int g = 0; g < 4; ++g) xv[g] = *(const ushort4*)(xb + (size_t)g * 1024);
  }

  for (int t = 0; t < SS; ++t) {
    // ---- obtain h(t): sentinel-poll own 16 x 8B units (the poll IS the load)
    unsigned long long uvv[16];
    if (t == 0) {
      const uint4* fsrc = zfrag + grp * 2048;
#pragma unroll
      for (int i = 0; i < 8; ++i) {
        uint4 v = fsrc[tid + 256 * i];
        uvv[2 * i]     = ((unsigned long long)v.y << 32) | v.x;
        uvv[2 * i + 1] = ((unsigned long long)v.w << 32) | v.z;
      }
    } else {
      const unsigned long long* q =
          (const unsigned long long*)(fragA + ((size_t)(t - 1) * 4 + grp) * 2048);
      unsigned pend = 0xFFFFu;
      do {
#pragma unroll
        for (int j = 0; j < 16; ++j) {
          if (pend & (1u << j)) {
            unsigned long long v = __hip_atomic_load(
                q + ((size_t)(tid + 256 * (j >> 1)) * 2 + (j & 1)),
                __ATOMIC_RELAXED, __HIP_MEMORY_SCOPE_AGENT);
            if (v != SENT) { uvv[j] = v; pend &= ~(1u << j); }
          }
        }
      } while (pend);
    }

    // ---- stage full 32KB tile (fragment-linear, conflict-free) ----
#pragma unroll
    for (int i = 0; i < 8; ++i) {
      uint4 sw;
      sw.x = (unsigned)uvv[2 * i];     sw.y = (unsigned)(uvv[2 * i] >> 32);
      sw.z = (unsigned)uvv[2 * i + 1]; sw.w = (unsigned)(uvv[2 * i + 1] >> 32);
      *(uint4*)&htile[(size_t)(tid + 256 * i) * 8] = sw;
    }
    __syncthreads();

    // xi(t+1) prefetch (wave 0) — consumed NEXT step
    ushort4 xn[4] = {};
    if (w == 0) {
      int tn = (t + 1 < SS) ? t + 1 : t;
      const ushort* xb = xi + ((size_t)tn * 64 + brow0 + eb) * G4 + pc;
#pragma unroll
      for (int g = 0; g < 4; ++g) xn[g] = *(const ushort4*)(xb + (size_t)g * 1024);
    }

    // ---- 32 k-chunks: fa from LDS (conflict-free), fb regs/L2 ----
    f32x4 acc0 = {}, acc1 = {};
#pragma unroll
    for (int k = 0; k < 32; k += 2) {
      bf8_t fa0 = *(const bf8_t*)&htile[(k * 64 + lane) * 8];
      bf8_t fa1 = *(const bf8_t*)&htile[((k + 1) * 64 + lane) * 8];
      acc0 = __builtin_amdgcn_mfma_f32_16x16x32_bf16(fa0, fbr[k], acc0, 0, 0, 0);
      acc1 = __builtin_amdgcn_mfma_f32_16x16x32_bf16(fa1, fbr[k + 1], acc1, 0, 0, 0);
    }
#pragma unroll
    for (int r = 0; r < 4; ++r)
      zbuf[w][kq * 4 + r][lr] = acc0[r] + acc1[r];
    __syncthreads();

    // ---- epilogue (wave 0): gates, c update, publish (fire-and-forget) ----
    if (w == 0) {
      f32x4 zi4 = *(const f32x4*)&zbuf[0][eb][en4];
      f32x4 zf4 = *(const f32x4*)&zbuf[1][eb][en4];
      f32x4 zg4 = *(const f32x4*)&zbuf[2][eb][en4];
      f32x4 zo4 = *(const f32x4*)&zbuf[3][eb][en4];
      union { unsigned long long u64; ushort u16[4]; uint2 u32x2; } ho;
#pragma unroll
      for (int j = 0; j < 4; ++j) {
        float zi = zi4[j] + bf2f(((const ushort*)&xv[0])[j]);
        float zf = zf4[j] + bf2f(((const ushort*)&xv[1])[j]);
        float zg = zg4[j] + bf2f(((const ushort*)&xv[2])[j]);
        float zo = zo4[j] + bf2f(((const ushort*)&xv[3])[j]);
        float si = 1.f / (1.f + __expf(-zi));
        float sf = 1.f / (1.f + __expf(-zf));
        float tg = tanhf(zg);
        float so = 1.f / (1.f + __expf(-zo));
        float c = sf * cr[j] + si * tg;
        cr[j] = c;
        ho.u16[j] = f2bf(so * tanhf(c));
      }
      // publish: atomic exchange performed at MALL; consumers see data (not
      // sentinel) exactly when it's valid — no ack, no flag, no fence.
      unsigned long long* fdst =
          (unsigned long long*)((char*)(fragA + ((size_t)t * 4 + grp) * 2048) +
                                pubu * 16 + pubb);
      unsigned long long old = __hip_atomic_exchange(
          fdst, ho.u64, __ATOMIC_RELAXED, __HIP_MEMORY_SCOPE_AGENT);
      asm volatile("" :: "v"(old));                    // keep return live
      // row-layout copy for k_logits (read only after kernel end)
      *(uint2*)(hs + (size_t)(t + 1) * BB * HH +
                (size_t)(brow0 + eb) * HH + pc) = ho.u32x2;
      xv[0] = xn[0]; xv[1] = xn[1]; xv[2] = xn[2]; xv[3] = xn[3];
    }
  }
}

// logits[b][t][a] = hs[t+1][b][:] . Wd_t[a][:] + bd[a]
__global__ __launch_bounds__(256) void k_logits(
    const ushort* __restrict__ hs1, const ushort* __restrict__ Wdt,
    const float* __restrict__ bd, float* __restrict__ out) {
  int gid = blockIdx.x * 256 + threadIdx.x;
  int a = gid & 15, row = gid >> 4;   // row = t*64+b
  int t = row >> 6, b = row & 63;
  const uint4* hp = (const uint4*)(hs1 + (size_t)row * HH);
  const uint4* wp = (const uint4*)(Wdt + (size_t)a * HH);
  float sum = 0.f;
#pragma unroll 4
  for (int i = 0; i < HH / 8; ++i) {
    uint4 hv = hp[i], wv = wp[i];
    const uint* hu = (const uint*)&hv;
    const uint* wu = (const uint*)&wv;
#pragma unroll
    for (int j = 0; j < 4; ++j) {
      sum += bf2f((ushort)(hu[j] & 0xffff)) * bf2f((ushort)(wu[j] & 0xffff));
      sum += bf2f((ushort)(hu[j] >> 16)) * bf2f((ushort)(wu[j] >> 16));
    }
  }
  out[32768 + ((size_t)b * SS + t) * 16 + a] = sum + bd[a];
}

extern "C" void kernel_launch(void* const* d_in, const int* in_sizes, int n_in,
                              void* d_out, int out_size, void* d_ws, size_t ws_size,
                              hipStream_t stream) {
  const int*   x    = (const int*)d_in[0];
  const float* etok = (const float*)d_in[4];
  const float* epos = (const float*)d_in[5];
  const float* Wi   = (const float*)d_in[6];
  const float* Wh   = (const float*)d_in[7];
  const float* bh   = (const float*)d_in[8];
  const float* Wd   = (const float*)d_in[9];
  const float* bd   = (const float*)d_in[10];

  char* ws = (char*)d_ws;
  size_t off = 0;
  ushort* Wi_t = (ushort*)(ws + off); off += (size_t)G4 * HH * 2;            // 8 MB
  ushort* Wh_t = (ushort*)(ws + off); off += (size_t)G4 * HH * 2;            // 8 MB
  ushort* Wd_t = (ushort*)(ws + off); off += 65536;                          // 64 KB
  // Ae (64 MB, dead after k_gemm_xi) aliases fragA (64 MB). The sentinel
  // memset sits between k_gemm_xi and k_recur in stream order; k_recur
  // accesses the region only via coherence-point atomics, so stale clean
  // L2 copies of Ae are unreachable.
  char* AeFrag = ws + off;            off += (size_t)512 * 4 * 2048 * 16;    // 64 MB
  ushort* Ae   = (ushort*)AeFrag;
  uint4*  fragA = (uint4*)AeFrag;
  ushort* xi   = (ushort*)(ws + off); off += (size_t)BB * SS * G4 * 2;       // 256 MB
  ushort* hs   = (ushort*)(ws + off); off += (size_t)(SS + 1) * BB * HH * 2; // 64.1 MB
  uint4*  zfrag = (uint4*)(ws + off); off += (size_t)4 * 2048 * 16;          // 128 KB

  hipMemsetAsync(d_out, 0, (size_t)out_size * 4, stream);          // dummies = 0
  hipMemsetAsync(zfrag, 0, (size_t)4 * 2048 * 16, stream);         // h(0) = 0

  dim3 b256(256);
  k_transpose_cast<<<dim3(G4 / 32, HH / 32), b256, 0, stream>>>(Wi, Wi_t, HH, G4);
  k_transpose_cast<<<dim3(G4 / 32, HH / 32), b256, 0, stream>>>(Wh, Wh_t, HH, G4);
  k_transpose_cast<<<dim3(1, HH / 32), b256, 0, stream>>>(Wd, Wd_t, HH, 16);
  k_embed<<<BB * SS, b256, 0, stream>>>(x, etok, epos, Ae);
  k_gemm_xi<<<dim3(G4 / 128, BB * SS / 128), b256, 0, stream>>>(Ae, Wi_t, bh, xi, G4);
  // re-sentinel fragA EVERY call (harness replays without re-poisoning)
  hipMemsetAsync(fragA, 0x7F, (size_t)512 * 4 * 2048 * 16, stream);
  k_recur<<<256, b256, 0, stream>>>(Wh_t, xi, hs, fragA, zfrag);
  k_logits<<<BB * SS * 16 / 256, b256, 0, stream>>>(hs + (size_t)BB * HH, Wd_t, bd,
                                                    (float*)d_out);
}

// Round 10
// 2839.385 us; speedup vs baseline: 1.2374x; 1.2374x over previous
//
#include <hip/hip_runtime.h>
#include <hip/hip_bf16.h>

#define BB 64
#define SS 512
#define HH 1024
#define G4 4096

using bf8_t = __attribute__((ext_vector_type(8))) short;   // 8 bf16 (4 VGPRs)
using f32x4 = __attribute__((ext_vector_type(4))) float;   // 4 fp32 acc
typedef unsigned long long ull;

__device__ inline ushort f2bf(float f) {
  __hip_bfloat16 h = __float2bfloat16(f);
  return *reinterpret_cast<ushort*>(&h);
}
__device__ inline float bf2f(ushort u) {
  unsigned v = ((unsigned)u) << 16;
  return __uint_as_float(v);
}

// fp32 [R][C] -> bf16 [C][R]
__global__ __launch_bounds__(256) void k_transpose_cast(
    const float* __restrict__ in, ushort* __restrict__ out, int R, int C) {
  __shared__ float tile[32][33];
  int c0 = blockIdx.x * 32, r0 = blockIdx.y * 32;
  int tx = threadIdx.x & 31, ty = threadIdx.x >> 5;  // 32 x 8
  for (int i = ty; i < 32; i += 8) {
    int r = r0 + i, c = c0 + tx;
    tile[i][tx] = (r < R && c < C) ? in[(size_t)r * C + c] : 0.f;
  }
  __syncthreads();
  for (int i = ty; i < 32; i += 8) {
    int c = c0 + i, r = r0 + tx;
    if (c < C && r < R) out[(size_t)c * R + r] = f2bf(tile[tx][i]);
  }
}

// Ae[row = t*64+b][k] = embed_tok[x[b][t]][k] + embed_pos[t][k], bf16
__global__ __launch_bounds__(256) void k_embed(
    const int* __restrict__ x, const float* __restrict__ etok,
    const float* __restrict__ epos, ushort* __restrict__ Ae) {
  int row = blockIdx.x;
  int t = row >> 6, b = row & 63;
  int tok = x[b * SS + t];
  const float4* tp = (const float4*)(etok + (size_t)tok * HH);
  const float4* pp = (const float4*)(epos + (size_t)t * HH);
  int i = threadIdx.x;  // 256 threads * float4 = 1024
  float4 a = tp[i], p = pp[i];
  ushort4 r = make_ushort4(f2bf(a.x + p.x), f2bf(a.y + p.y),
                           f2bf(a.z + p.z), f2bf(a.w + p.w));
  ((ushort4*)(Ae + (size_t)row * HH))[i] = r;
}

// C[m][n] (bf16) = A[m][k] @ Bt[n][k]^T + bias[n].  M,N mult of 128, K=1024.
__global__ __launch_bounds__(256) void k_gemm_xi(
    const ushort* __restrict__ Ag, const ushort* __restrict__ Bt,
    const float* __restrict__ bias, ushort* __restrict__ Cout, int N) {
  __shared__ alignas(16) ushort As[128 * 40];   // rows padded 32->40 shorts
  __shared__ alignas(16) ushort Bs[128 * 40];
  const int m0 = blockIdx.y * 128, n0 = blockIdx.x * 128;
  const int tid = threadIdx.x;
  const int srow = tid >> 1, shalf = tid & 1;   // stage: 2 thr/row, 16 shorts each
  const int w = tid >> 6, lane = tid & 63;
  const int wm = w >> 1, wn = w & 1;            // 2x2 waves, 64x64 each
  const int lr = lane & 15, kq = lane >> 4;
  f32x4 acc[4][4] = {};
  for (int k0 = 0; k0 < HH; k0 += 32) {
    const uint4* ga = (const uint4*)(Ag + (size_t)(m0 + srow) * HH + k0 + shalf * 16);
    const uint4* gb = (const uint4*)(Bt + (size_t)(n0 + srow) * HH + k0 + shalf * 16);
    uint4 va0 = ga[0], va1 = ga[1];
    uint4 vb0 = gb[0], vb1 = gb[1];
    __syncthreads();
    *(uint4*)&As[srow * 40 + shalf * 16]     = va0;
    *(uint4*)&As[srow * 40 + shalf * 16 + 8] = va1;
    *(uint4*)&Bs[srow * 40 + shalf * 16]     = vb0;
    *(uint4*)&Bs[srow * 40 + shalf * 16 + 8] = vb1;
    __syncthreads();
    bf8_t fa[4], fb[4];
#pragma unroll
    for (int i = 0; i < 4; ++i) {
      fa[i] = *(const bf8_t*)&As[(wm * 64 + i * 16 + lr) * 40 + kq * 8];
      fb[i] = *(const bf8_t*)&Bs[(wn * 64 + i * 16 + lr) * 40 + kq * 8];
    }
#pragma unroll
    for (int mi = 0; mi < 4; ++mi)
#pragma unroll
      for (int ni = 0; ni < 4; ++ni)
        acc[mi][ni] = __builtin_amdgcn_mfma_f32_16x16x32_bf16(fa[mi], fb[ni], acc[mi][ni], 0, 0, 0);
  }
#pragma unroll
  for (int mi = 0; mi < 4; ++mi) {
    int grow = m0 + wm * 64 + mi * 16 + kq * 4;
#pragma unroll
    for (int ni = 0; ni < 4; ++ni) {
      int gcol = n0 + wn * 64 + ni * 16 + lr;
      float bv = bias[gcol];
#pragma unroll
      for (int r = 0; r < 4; ++r)
        Cout[(size_t)(grow + r) * N + gcol] = f2bf(acc[mi][ni][r] + bv);
    }
  }
}

// Persistent recurrence, 4 batch groups x 64 column-owner WGs, 256 thr.
// Mixed-gate B layout: wave w, lane (kq,lr): gate = lr>>2, col = n0+4w+(lr&3).
// MFMA output -> all 4 gates of a (row,col) live in 4 lanes of the SAME wave
// -> shfl_xor gather, fully parallel epilogue, no zbuf, 2 barriers/step.
// Transport: sentinel data-is-flag (fragA pre-set 0x7F..; |h|<1 can't collide).
// Publish = fire-and-forget 8B agent atomic exchange (performed at MALL);
// poll = BATCHED 16x 8B relaxed atomic loads per round (1 RT/round).
__global__ __launch_bounds__(256, 1) void k_recur(
    const ushort* __restrict__ Wh_t,   // [4096][1024] bf16
    const ushort* __restrict__ xi,     // [S*64][4096] bf16 (bh folded in)
    ushort* __restrict__ hs,           // [(S+1)*64][1024] bf16 row layout
    uint4* __restrict__ fragA) {       // [512][4][2048] 16B units: h(t+1) at t
  __shared__ alignas(16) ushort htile[2048 * 8];   // 32 KiB
  __shared__ ushort hxch[4][16][4];                // 512 B wave-local transpose
  const ull SENT = 0x7F7F7F7F7F7F7F7FULL;
  const int grp = blockIdx.x >> 6;      // batch group 0..3
  const int mem = blockIdx.x & 63;      // member (column owner)
  const int n0 = mem * 16;
  const int brow0 = grp * 16;
  const int tid = threadIdx.x;
  const int w = tid >> 6, lane = tid & 63;
  const int lr = lane & 15, kq = lane >> 4;
  const int gate = lr >> 2;
  const int c0 = n0 + 4 * w;            // wave's 4-col base
  const int col = c0 + (lr & 3);
  const int gc = gate * 1024 + col;     // gate-col in [0,4096)

  // fb fragments via inline-asm loads -> cannot be rematerialized (pinned)
  bf8_t fbr[32];
  {
    const ushort* wrow = Wh_t + (size_t)gc * HH + kq * 8;
#pragma unroll
    for (int k = 0; k < 32; ++k)
      asm volatile("global_load_dwordx4 %0, %1, off offset:%c2"
                   : "=v"(fbr[k]) : "v"(wrow), "i"(k * 64));
    asm volatile("s_waitcnt vmcnt(0)" ::: "memory");
  }

  // publish precompute (lanes 0..15 publish): unit u = pk0*64+pq*16+row
  const int pk0 = c0 >> 5, pq = (c0 >> 3) & 3;
  const int pboff = (c0 & 7) * 2;       // 0 or 8

  float cr[4] = {0.f, 0.f, 0.f, 0.f};   // c-state (4 rows, consistent copies)

  // xi(0) preload: xi[row=brow0+kq*4+r][gc], r=0..3
  ushort xv[4];
  {
    const ushort* xr = xi + ((size_t)brow0 + kq * 4) * G4 + gc;
#pragma unroll
    for (int r = 0; r < 4; ++r) xv[r] = xr[(size_t)r * G4];
  }

  for (int t = 0; t < SS; ++t) {
    // ---- obtain h(t): batched sentinel poll (1 RT per round) ----
    ull uvv[16];
    if (t == 0) {
#pragma unroll
      for (int j = 0; j < 16; ++j) uvv[j] = 0;
    } else {
      const ull* q = (const ull*)(fragA + ((size_t)(t - 1) * 4 + grp) * 2048);
      bool again;
      do {
#pragma unroll
        for (int i = 0; i < 8; ++i) {   // unconditional: all 16 in flight
          uvv[2 * i]     = __hip_atomic_load(q + 2 * tid + 512 * i,
                              __ATOMIC_RELAXED, __HIP_MEMORY_SCOPE_AGENT);
          uvv[2 * i + 1] = __hip_atomic_load(q + 2 * tid + 512 * i + 1,
                              __ATOMIC_RELAXED, __HIP_MEMORY_SCOPE_AGENT);
        }
        again = false;
#pragma unroll
        for (int j = 0; j < 16; ++j) again |= (uvv[j] == SENT);
      } while (again);
    }
    __syncthreads();                    // A: all waves done reading old htile

    // ---- stage 32KB tile (fragment-linear, conflict-free) ----
#pragma unroll
    for (int i = 0; i < 8; ++i) {
      uint4 sw;
      sw.x = (unsigned)uvv[2 * i];     sw.y = (unsigned)(uvv[2 * i] >> 32);
      sw.z = (unsigned)uvv[2 * i + 1]; sw.w = (unsigned)(uvv[2 * i + 1] >> 32);
      *(uint4*)&htile[(size_t)(tid + 256 * i) * 8] = sw;
    }
    __syncthreads();                    // B: stage complete

    // xi(t+1) prefetch — consumed next step, hidden under MFMA
    ushort xn[4];
    {
      int tn = (t + 1 < SS) ? t + 1 : t;
      const ushort* xr = xi + ((size_t)tn * 64 + brow0 + kq * 4) * G4 + gc;
#pragma unroll
      for (int r = 0; r < 4; ++r) xn[r] = xr[(size_t)r * G4];
    }

    // ---- MFMA: 32 k-chunks, fa LDS conflict-free, fb pinned regs ----
    f32x4 acc0 = {}, acc1 = {};
#pragma unroll
    for (int k = 0; k < 32; k += 2) {
      bf8_t fa0 = *(const bf8_t*)&htile[(k * 64 + lane) * 8];
      bf8_t fa1 = *(const bf8_t*)&htile[((k + 1) * 64 + lane) * 8];
      acc0 = __builtin_amdgcn_mfma_f32_16x16x32_bf16(fa0, fbr[k], acc0, 0, 0, 0);
      acc1 = __builtin_amdgcn_mfma_f32_16x16x32_bf16(fa1, fbr[k + 1], acc1, 0, 0, 0);
    }

    // ---- parallel epilogue (all lanes) ----
    // lane holds z[gate][row=kq*4+r][col]; gather the 4 gates via shfl_xor
    float z[4], zb[4], zc[4], zd[4];
#pragma unroll
    for (int r = 0; r < 4; ++r) z[r] = acc0[r] + acc1[r] + bf2f(xv[r]);
#pragma unroll
    for (int r = 0; r < 4; ++r) {
      zb[r] = __shfl_xor(z[r], 4);
      zc[r] = __shfl_xor(z[r], 8);
      zd[r] = __shfl_xor(zb[r], 8);
    }
    ushort hvals[4];
#pragma unroll
    for (int r = 0; r < 4; ++r) {
      float zi = gate == 0 ? z[r] : gate == 1 ? zb[r] : gate == 2 ? zc[r] : zd[r];
      float zf = gate == 0 ? zb[r] : gate == 1 ? z[r] : gate == 2 ? zd[r] : zc[r];
      float zg = gate == 0 ? zc[r] : gate == 1 ? zd[r] : gate == 2 ? z[r] : zb[r];
      float zo = gate == 0 ? zd[r] : gate == 1 ? zc[r] : gate == 2 ? zb[r] : z[r];
      float si = 1.f / (1.f + __expf(-zi));
      float sf = 1.f / (1.f + __expf(-zf));
      float so = 1.f / (1.f + __expf(-zo));
      float tg = 1.f - 2.f / (1.f + __expf(2.f * zg));   // tanh
      float c  = sf * cr[r] + si * tg;
      cr[r] = c;
      float tc = 1.f - 2.f / (1.f + __expf(2.f * c));    // tanh
      hvals[r] = f2bf(so * tc);
    }
    // wave-local transpose: gate-0 lanes write (4 rows x 1 col each)
    if (lr < 4) {
#pragma unroll
      for (int r = 0; r < 4; ++r) hxch[w][kq * 4 + r][lr] = hvals[r];
    }
    // lanes 0..15: read (row=lane, 4 cols) and publish (same wave -> lgkmcnt)
    if (lane < 16) {
      uint2 ho8 = *(const uint2*)&hxch[w][lane][0];
      ull val = ((ull)ho8.y << 32) | ho8.x;
      char* fbase = (char*)(fragA + ((size_t)t * 4 + grp) * 2048);
      ull* fdst = (ull*)(fbase + (size_t)(pk0 * 64 + pq * 16 + lane) * 16 + pboff);
      __hip_atomic_exchange(fdst, val, __ATOMIC_RELAXED,
                            __HIP_MEMORY_SCOPE_AGENT);   // fire-and-forget
      // row-layout copy for k_logits (read only after kernel end)
      *(uint2*)(hs + ((size_t)(t + 1) * 64 + brow0 + lane) * HH + c0) = ho8;
    }
    xv[0] = xn[0]; xv[1] = xn[1]; xv[2] = xn[2]; xv[3] = xn[3];
  }
}

// logits[b][t][a] = hs[t+1][b][:] . Wd_t[a][:] + bd[a]
__global__ __launch_bounds__(256) void k_logits(
    const ushort* __restrict__ hs1, const ushort* __restrict__ Wdt,
    const float* __restrict__ bd, float* __restrict__ out) {
  int gid = blockIdx.x * 256 + threadIdx.x;
  int a = gid & 15, row = gid >> 4;   // row = t*64+b
  int t = row >> 6, b = row & 63;
  const uint4* hp = (const uint4*)(hs1 + (size_t)row * HH);
  const uint4* wp = (const uint4*)(Wdt + (size_t)a * HH);
  float sum = 0.f;
#pragma unroll 4
  for (int i = 0; i < HH / 8; ++i) {
    uint4 hv = hp[i], wv = wp[i];
    const uint* hu = (const uint*)&hv;
    const uint* wu = (const uint*)&wv;
#pragma unroll
    for (int j = 0; j < 4; ++j) {
      sum += bf2f((ushort)(hu[j] & 0xffff)) * bf2f((ushort)(wu[j] & 0xffff));
      sum += bf2f((ushort)(hu[j] >> 16)) * bf2f((ushort)(wu[j] >> 16));
    }
  }
  out[32768 + ((size_t)b * SS + t) * 16 + a] = sum + bd[a];
}

extern "C" void kernel_launch(void* const* d_in, const int* in_sizes, int n_in,
                              void* d_out, int out_size, void* d_ws, size_t ws_size,
                              hipStream_t stream) {
  const int*   x    = (const int*)d_in[0];
  const float* etok = (const float*)d_in[4];
  const float* epos = (const float*)d_in[5];
  const float* Wi   = (const float*)d_in[6];
  const float* Wh   = (const float*)d_in[7];
  const float* bh   = (const float*)d_in[8];
  const float* Wd   = (const float*)d_in[9];
  const float* bd   = (const float*)d_in[10];

  char* ws = (char*)d_ws;
  size_t off = 0;
  ushort* Wi_t = (ushort*)(ws + off); off += (size_t)G4 * HH * 2;            // 8 MB
  ushort* Wh_t = (ushort*)(ws + off); off += (size_t)G4 * HH * 2;            // 8 MB
  ushort* Wd_t = (ushort*)(ws + off); off += 65536;                          // 64 KB
  // Ae (64 MB, dead after k_gemm_xi) aliases fragA (64 MB). The sentinel
  // memset sits between k_gemm_xi and k_recur in stream order; k_recur
  // touches the region only via coherence-point atomics.
  char* AeFrag = ws + off;            off += (size_t)512 * 4 * 2048 * 16;    // 64 MB
  ushort* Ae   = (ushort*)AeFrag;
  uint4*  fragA = (uint4*)AeFrag;
  ushort* xi   = (ushort*)(ws + off); off += (size_t)BB * SS * G4 * 2;       // 256 MB
  ushort* hs   = (ushort*)(ws + off); off += (size_t)(SS + 1) * BB * HH * 2; // 64.1 MB

  hipMemsetAsync(d_out, 0, (size_t)out_size * 4, stream);          // dummies = 0

  dim3 b256(256);
  k_transpose_cast<<<dim3(G4 / 32, HH / 32), b256, 0, stream>>>(Wi, Wi_t, HH, G4);
  k_transpose_cast<<<dim3(G4 / 32, HH / 32), b256, 0, stream>>>(Wh, Wh_t, HH, G4);
  k_transpose_cast<<<dim3(1, HH / 32), b256, 0, stream>>>(Wd, Wd_t, HH, 16);
  k_embed<<<BB * SS, b256, 0, stream>>>(x, etok, epos, Ae);
  k_gemm_xi<<<dim3(G4 / 128, BB * SS / 128), b256, 0, stream>>>(Ae, Wi_t, bh, xi, G4);
  // re-sentinel fragA EVERY call (harness replays without re-poisoning)
  hipMemsetAsync(fragA, 0x7F, (size_t)512 * 4 * 2048 * 16, stream);
  k_recur<<<256, b256, 0, stream>>>(Wh_t, xi, hs, fragA);
  k_logits<<<BB * SS * 16 / 256, b256, 0, stream>>>(hs + (size_t)BB * HH, Wd_t, bd,
                                                    (float*)d_out);
}